// Round 9
// baseline (394.313 us; speedup 1.0000x reference)
//
#include <hip/hip_runtime.h>
#include <hip/hip_bf16.h>

#define S_LEN 2048
#define D_DIM 64
#define QT    64
#define KT    64
#define NTHR  256
#define NKT   (S_LEN / KT)          // 32
#define NBLK  1024                  // 32 q-tiles * 32 bh
#define PROB_ELEMS 4194304LL        // 2*16*2048*64

typedef float        f32x4  __attribute__((ext_vector_type(4)));
typedef int          i32x4  __attribute__((ext_vector_type(4)));
typedef unsigned int u32x4  __attribute__((ext_vector_type(4)));
typedef short        bf16x8 __attribute__((ext_vector_type(8)));

__device__ __forceinline__ unsigned short f2bf(float f) {
    return __builtin_bit_cast(unsigned short, __float2bfloat16(f));
}
__device__ __forceinline__ int swzc(int row, int ch) {
    return ch ^ ((row ^ (row >> 3)) & 7);
}
__device__ __forceinline__ float4 scale4(float4 v, float s) {
    v.x *= s; v.y *= s; v.z *= s; v.w *= s; return v;
}
__device__ __forceinline__ u32x4 packbf(float4 a, float4 b) {
    u32x4 r;
    r[0] = (unsigned)f2bf(a.x) | ((unsigned)f2bf(a.y) << 16);
    r[1] = (unsigned)f2bf(a.z) | ((unsigned)f2bf(a.w) << 16);
    r[2] = (unsigned)f2bf(b.x) | ((unsigned)f2bf(b.y) << 16);
    r[3] = (unsigned)f2bf(b.z) | ((unsigned)f2bf(b.w) << 16);
    return r;
}
__device__ __forceinline__ unsigned cvtpk(float lo, float hi) {
    unsigned r;
    asm("v_cvt_pk_bf16_f32 %0, %1, %2" : "=v"(r) : "v"(lo), "v"(hi));
    return r;
}
#define BC8(x) __builtin_bit_cast(bf16x8, (x))

// -------------------------------------------------------------------------
__global__ void mask_probe_kernel(const unsigned int* __restrict__ m,
                                  int* __restrict__ flag) {
    unsigned int v = m[threadIdx.x];
    unsigned long long ok = __ballot(v <= 1u);
    if (threadIdx.x == 0) *flag = (ok == ~0ULL) ? 1 : 0;
}

// -------------------------------------------------------------------------
// Prep: K and V rewritten in MFMA-FRAGMENT-LINEAR order.
// K tile (bh,kt): frag (n,f), lane l=(g,c): bf16x8 = K[kt*64+n*16+c][f*32+8g..+7]
//   u32 offset: (bh*32+kt)*2048 + ((n*2+f)*64 + l)*4
// V tile: frag (kb,df), lane l=(g,c): bf16x8 = V[32kb+8g+j][df*16+c], j=0..7
//   u32 offset: (bh*32+kt)*2048 + ((kb*4+df)*64 + l)*4
// A wave reads one frag as 64 consecutive 16B chunks = 1KB coalesced.
// -------------------------------------------------------------------------
#define KFRAG_T 524288   // 32bh*32kt*4n*2f*64lane
#define VFRAG_T 65536    // 32bh*32kt*64lane
__global__ __launch_bounds__(256)
void kv_prep_frag(const float* __restrict__ Kg, const float* __restrict__ Vg,
                  unsigned* __restrict__ Kf, unsigned* __restrict__ Vf) {
    int tid = blockIdx.x * 256 + threadIdx.x;
    if (tid < KFRAG_T) {
        int l = tid & 63, f = (tid >> 6) & 1, n = (tid >> 7) & 3;
        int kt = (tid >> 9) & 31, bh = tid >> 14;
        int c = l & 15, g = l >> 4;
        const float* src = Kg + (long long)(bh * S_LEN + kt * KT + n * 16 + c) * D_DIM
                              + f * 32 + g * 8;
        float4 a = *(const float4*)src, b = *(const float4*)(src + 4);
        unsigned* dst = Kf + ((unsigned)(bh * NKT + kt) << 11)
                           + (unsigned)((n * 2 + f) * 64 + l) * 4u;
        *(u32x4*)dst = packbf(a, b);
    } else if (tid < KFRAG_T + VFRAG_T) {
        int idx = tid - KFRAG_T;
        int l = idx & 63, kt = (idx >> 6) & 31, bh = idx >> 11;
        int c = l & 15, g = l >> 4;
        const float* vb = Vg + (long long)(bh * S_LEN + kt * KT) * D_DIM;
        unsigned* tile = Vf + ((unsigned)(bh * NKT + kt) << 11);
        #pragma unroll
        for (int kb = 0; kb < 2; ++kb)
            #pragma unroll
            for (int df = 0; df < 4; ++df) {
                u32x4 o;
                #pragma unroll
                for (int s = 0; s < 4; ++s) {
                    int k0 = kb * 32 + g * 8 + 2 * s;
                    float lo = vb[k0 * D_DIM + df * 16 + c];
                    float hi = vb[(k0 + 1) * D_DIM + df * 16 + c];
                    o[s] = (unsigned)f2bf(lo) | ((unsigned)f2bf(hi) << 16);
                }
                *(u32x4*)(tile + (unsigned)((kb * 4 + df) * 64 + l) * 4u) = o;
            }
    }
}

// ---- fragment loads (barrier-free, coalesced 1KB per frag) ----
#define LOAD_KFRAG(DST, KTV)                                                \
    { const u32x4* p_ = (const u32x4*)(Kf + fbase + (unsigned)(KTV) * 2048u) + lane; \
      _Pragma("unroll")                                                     \
      for (int i_ = 0; i_ < 8; ++i_) DST[i_] = p_[i_ * 64]; }

#define LOAD_VFRAG(DST, KTV)                                                \
    { const u32x4* p_ = (const u32x4*)(Vf + fbase + (unsigned)(KTV) * 2048u) + lane; \
      _Pragma("unroll")                                                     \
      for (int i_ = 0; i_ < 8; ++i_) DST[i_] = p_[i_ * 64]; }

#define LOAD_M4(DST, KTV)                                                   \
    { _Pragma("unroll")                                                     \
      for (int n_ = 0; n_ < 4; ++n_)                                        \
        DST[n_] = *(const i32x4*)(maskI + rowoff + (unsigned)((KTV) * KT + n_ * 16 + 4 * g)); }

#define BITS_FROM_M4(DST, M)                                                \
    { unsigned bz_ = 0u;                                                    \
      _Pragma("unroll")                                                     \
      for (int n_ = 0; n_ < 4; ++n_)                                        \
        bz_ |= ((M[n_][0] ? 1u : 0u) | (M[n_][1] ? 2u : 0u) |               \
                (M[n_][2] ? 4u : 0u) | (M[n_][3] ? 8u : 0u)) << (n_ * 4);   \
      (DST) = bz_; }

#define LOAD_MBITS(DST, KTV)                                                \
    { unsigned bz_ = 0u;                                                    \
      _Pragma("unroll")                                                     \
      for (int n_ = 0; n_ < 4; ++n_) {                                      \
        unsigned idx_ = rowoff + (unsigned)((KTV) * KT + n_ * 16 + 4 * g);  \
        if (mask32) {                                                       \
            i32x4 m4_ = *(const i32x4*)(maskI + idx_);                      \
            bz_ |= ((m4_[0] ? 1u : 0u) | (m4_[1] ? 2u : 0u) |               \
                    (m4_[2] ? 4u : 0u) | (m4_[3] ? 8u : 0u)) << (n_ * 4);   \
        } else {                                                            \
            unsigned mb_ = *(const unsigned*)(maskB + idx_);                \
            bz_ |= (((mb_ & 0xffu) ? 1u : 0u) | ((mb_ & 0xff00u) ? 2u : 0u) | \
                    ((mb_ & 0xff0000u) ? 4u : 0u) |                         \
                    ((mb_ & 0xff000000u) ? 8u : 0u)) << (n_ * 4);           \
        } }                                                                 \
      (DST) = bz_; }

#define LOAD_BITS2(DST, KTV)                                                \
    { if (useWS) (DST) = (unsigned)bitsWS[bitbase + (unsigned)(KTV) * NTHR];\
      else LOAD_MBITS(DST, KTV) }

#define QK_FRAG(KC, ACC)                                                    \
    { _Pragma("unroll")                                                     \
      for (int n_ = 0; n_ < 4; ++n_) {                                      \
        f32x4 a_ = {0.f, 0.f, 0.f, 0.f};                                    \
        a_ = __builtin_amdgcn_mfma_f32_16x16x32_bf16(BC8(KC[2*n_]),   qf0, a_, 0, 0, 0); \
        a_ = __builtin_amdgcn_mfma_f32_16x16x32_bf16(BC8(KC[2*n_+1]), qf1, a_, 0, 0, 0); \
        ACC[n_] = a_; } }

#define PH1_FRAG(KC, BITS)                                                  \
    { unsigned bb_ = (BITS);                                                \
      _Pragma("unroll")                                                     \
      for (int n_ = 0; n_ < 4; ++n_) {                                      \
        f32x4 a_ = {0.f, 0.f, 0.f, 0.f};                                    \
        a_ = __builtin_amdgcn_mfma_f32_16x16x32_bf16(BC8(KC[2*n_]),   qf0, a_, 0, 0, 0); \
        a_ = __builtin_amdgcn_mfma_f32_16x16x32_bf16(BC8(KC[2*n_+1]), qf1, a_, 0, 0, 0); \
        unsigned mb_ = bb_ >> (n_ * 4);                                     \
        float e0_ = (mb_ & 1u) ? 0.f : __expf(a_[0]);                       \
        float e1_ = (mb_ & 2u) ? 0.f : __expf(a_[1]);                       \
        float e2_ = (mb_ & 4u) ? 0.f : __expf(a_[2]);                       \
        float e3_ = (mb_ & 8u) ? 0.f : __expf(a_[3]);                       \
        psum += (e0_ + e1_) + (e2_ + e3_); } }

#define SM_P(ACC, BITS, KTV)                                                \
    { unsigned bb_ = (BITS);                                                \
      _Pragma("unroll")                                                     \
      for (int n_ = 0; n_ < 4; ++n_) {                                      \
        f32x4 a_ = ACC[n_]; unsigned mb_ = bb_ >> (n_ * 4);                 \
        f32x4 ev_;                                                          \
        ev_[0] = (mb_ & 1u) ? 0.f : __expf(a_[0]) * rinv;                   \
        ev_[1] = (mb_ & 2u) ? 0.f : __expf(a_[1]) * rinv;                   \
        ev_[2] = (mb_ & 4u) ? 0.f : __expf(a_[2]) * rinv;                   \
        ev_[3] = (mb_ & 8u) ? 0.f : __expf(a_[3]) * rinv;                   \
        unsigned idx0_ = rowoff + (unsigned)((KTV) * KT + n_ * 16 + 4 * g); \
        __builtin_nontemporal_store(ev_, (f32x4*)(attnOut + idx0_));        \
        uint2 pk_; pk_.x = cvtpk(ev_[0], ev_[1]); pk_.y = cvtpk(ev_[2], ev_[3]); \
        int kloc_ = n_ * 16 + 4 * g;                                        \
        *(uint2*)(Ps + ql * 128 + swzc(ql, kloc_ >> 3) * 16 + (kloc_ & 7) * 2) = pk_; } }

#define PV_FRAG(VC)                                                         \
    { bf16x8 pa0_ = *(const bf16x8*)(Ps + ql * 128 + swzc(ql, g) * 16);     \
      bf16x8 pa1_ = *(const bf16x8*)(Ps + ql * 128 + swzc(ql, 4 + g) * 16); \
      __builtin_amdgcn_s_setprio(1);                                        \
      _Pragma("unroll")                                                     \
      for (int df_ = 0; df_ < 4; ++df_) {                                   \
        pacc[df_] = __builtin_amdgcn_mfma_f32_16x16x32_bf16(pa0_, BC8(VC[df_]),     pacc[df_], 0, 0, 0); \
        pacc[df_] = __builtin_amdgcn_mfma_f32_16x16x32_bf16(pa1_, BC8(VC[4 + df_]), pacc[df_], 0, 0, 0); } \
      __builtin_amdgcn_s_setprio(0); }

// -------------------------------------------------------------------------
// Barrier-free fused kernel: frags straight from global, LDS = Ps only.
// -------------------------------------------------------------------------
__global__ __launch_bounds__(NTHR, 3)
void attn_fused_frag(const float* __restrict__ Qg,
                     const unsigned* __restrict__ Kf,
                     const unsigned* __restrict__ Vf,
                     const unsigned char* __restrict__ maskB,
                     const int* __restrict__ flagp,
                     unsigned short* __restrict__ bitsWS, int useWS,
                     float* __restrict__ attnOut, float* __restrict__ probOut) {
    __shared__ unsigned char Ps[8192];   // 64 q x 64 k bf16 (aliases Q stage)

    const int t = threadIdx.x;
    const int lane = t & 63, w = t >> 6, c = lane & 15, g = lane >> 4;

    const int orig = blockIdx.x;
    const int virt = (orig & 7) * 128 + (orig >> 3);   // XCD swizzle
    const int qt = virt & 31, bh = virt >> 5;
    const int mask32 = *flagp;
    const int* maskI = (const int*)maskB;

    const int qrowbase = bh * S_LEN + qt * QT;
    const int ql = w * 16 + c;
    const unsigned rowoff = (unsigned)(qrowbase + ql) * (unsigned)S_LEN;
    const unsigned bitbase = (unsigned)virt * NKT * NTHR + (unsigned)t;
    const unsigned fbase = (unsigned)(bh * NKT) << 11;   // u32 idx of tile 0

    // ---- stage Q (pre-scaled by 1/8) into Ps, keep fragments ----
    #pragma unroll
    for (int i = 0; i < 2; ++i) {
        int flat = i * NTHR + t, row = flat >> 3, ch = flat & 7;
        const float* src = Qg + (qrowbase + row) * D_DIM + ch * 8;
        float4 a = *(const float4*)src, b = *(const float4*)(src + 4);
        *(u32x4*)(Ps + row * 128 + swzc(row, ch) * 16) =
            packbf(scale4(a, 0.125f), scale4(b, 0.125f));
    }
    __syncthreads();   // the ONLY barrier in this kernel
    bf16x8 qf0 = *(const bf16x8*)(Ps + ql * 128 + swzc(ql, g) * 16);
    bf16x8 qf1 = *(const bf16x8*)(Ps + ql * 128 + swzc(ql, 4 + g) * 16);
    // After this point Ps rows are wave-private (wave w touches rows w*16..+15
    // only) -- no further __syncthreads needed anywhere.

    // =================== PHASE 1: rowsum + mask bits ===================
    float psum = 0.f;
    {
        u32x4 kA[8], kB[8];
        i32x4 mA[4], mB[4];
        unsigned bA, bB;
        LOAD_KFRAG(kA, 0)
        if (mask32) { LOAD_M4(mA, 0) }

        for (int j = 0; j < NKT / 2; ++j) {
            const int ktA = 2 * j, ktB = 2 * j + 1;
            LOAD_KFRAG(kB, ktB)
            if (mask32) { LOAD_M4(mB, ktB) BITS_FROM_M4(bA, mA) }
            else        { LOAD_MBITS(bA, ktA) }
            PH1_FRAG(kA, bA)
            if (useWS) bitsWS[bitbase + (unsigned)ktA * NTHR] = (unsigned short)bA;

            if (j + 1 < NKT / 2) {
                LOAD_KFRAG(kA, ktA + 2)
                if (mask32) { LOAD_M4(mA, ktA + 2) }
            }
            if (mask32) { BITS_FROM_M4(bB, mB) }
            else        { LOAD_MBITS(bB, ktB) }
            PH1_FRAG(kB, bB)
            if (useWS) bitsWS[bitbase + (unsigned)ktB * NTHR] = (unsigned short)bB;
        }
    }
    float s = psum;
    s += __shfl_xor(s, 16, 64);
    s += __shfl_xor(s, 32, 64);
    const float rinv = 1.0f / s;

    // =================== PHASE 2: attn + PV ===================
    f32x4 pacc[4];
    #pragma unroll
    for (int d = 0; d < 4; ++d) pacc[d] = (f32x4){0.f, 0.f, 0.f, 0.f};

    {
        u32x4 kA[8], kB[8], vA[8], vB[8];
        f32x4 accA[4], accB[4];
        unsigned bA, bB;
        LOAD_KFRAG(kA, 0)
        LOAD_BITS2(bA, 0)

        for (int j = 0; j < NKT / 2; ++j) {
            const int ktA = 2 * j, ktB = 2 * j + 1;
            LOAD_KFRAG(kB, ktB)
            LOAD_BITS2(bB, ktB)
            QK_FRAG(kA, accA)
            LOAD_VFRAG(vA, ktA)          // lands under exp/pack below
            SM_P(accA, bA, ktA)
            PV_FRAG(vA)

            if (j + 1 < NKT / 2) {
                LOAD_KFRAG(kA, ktA + 2)
                LOAD_BITS2(bA, ktA + 2)
            }
            QK_FRAG(kB, accB)
            LOAD_VFRAG(vB, ktB)
            SM_P(accB, bB, ktB)
            PV_FRAG(vB)
        }
    }

    #pragma unroll
    for (int df = 0; df < 4; ++df)
        #pragma unroll
        for (int r = 0; r < 4; ++r) {
            int qe = w * 16 + g * 4 + r;
            probOut[(long long)(qrowbase + qe) * D_DIM + df * 16 + c] = pacc[df][r];
        }
}

// -------------------------------------------------------------------------
// Fallback (R8 register-staging kernel) if ws too small for prep images.
// -------------------------------------------------------------------------
#define PH1_TILE(KS, BITS)                                                  \
    { unsigned bb = (BITS);                                                 \
      _Pragma("unroll")                                                     \
      for (int n = 0; n < 4; ++n) {                                         \
        int rowk = n * 16 + c;                                              \
        bf16x8 kf0 = *(const bf16x8*)((KS) + rowk * 128 + swzc(rowk, g) * 16);     \
        bf16x8 kf1 = *(const bf16x8*)((KS) + rowk * 128 + swzc(rowk, 4 + g) * 16); \
        f32x4 acc = {0.f, 0.f, 0.f, 0.f};                                   \
        acc = __builtin_amdgcn_mfma_f32_16x16x32_bf16(kf0, qf0, acc, 0, 0, 0); \
        acc = __builtin_amdgcn_mfma_f32_16x16x32_bf16(kf1, qf1, acc, 0, 0, 0); \
        unsigned mb = bb >> (n * 4);                                        \
        psum += (mb & 1u) ? 0.f : __expf(acc[0]);                           \
        psum += (mb & 2u) ? 0.f : __expf(acc[1]);                           \
        psum += (mb & 4u) ? 0.f : __expf(acc[2]);                           \
        psum += (mb & 8u) ? 0.f : __expf(acc[3]);                           \
      } }

#define PH2_TILE(KS, VT, BITS, KTV)                                         \
    { unsigned bb = (BITS);                                                 \
      _Pragma("unroll")                                                     \
      for (int n = 0; n < 4; ++n) {                                         \
        int rowk = n * 16 + c;                                              \
        bf16x8 kf0 = *(const bf16x8*)((KS) + rowk * 128 + swzc(rowk, g) * 16);     \
        bf16x8 kf1 = *(const bf16x8*)((KS) + rowk * 128 + swzc(rowk, 4 + g) * 16); \
        f32x4 acc = {0.f, 0.f, 0.f, 0.f};                                   \
        acc = __builtin_amdgcn_mfma_f32_16x16x32_bf16(kf0, qf0, acc, 0, 0, 0); \
        acc = __builtin_amdgcn_mfma_f32_16x16x32_bf16(kf1, qf1, acc, 0, 0, 0); \
        unsigned mb = bb >> (n * 4);                                        \
        f32x4 ev;                                                           \
        ev[0] = (mb & 1u) ? 0.f : __expf(acc[0]) * rinv;                    \
        ev[1] = (mb & 2u) ? 0.f : __expf(acc[1]) * rinv;                    \
        ev[2] = (mb & 4u) ? 0.f : __expf(acc[2]) * rinv;                    \
        ev[3] = (mb & 8u) ? 0.f : __expf(acc[3]) * rinv;                    \
        unsigned idx0 = rowoff + (unsigned)((KTV) * KT + n * 16 + 4 * g);   \
        __builtin_nontemporal_store(ev, (f32x4*)(attnOut + idx0));          \
        uint2 pkv; pkv.x = cvtpk(ev[0], ev[1]); pkv.y = cvtpk(ev[2], ev[3]);\
        int kloc = n * 16 + 4 * g;                                          \
        *(uint2*)(Ps + ql * 128 + swzc(ql, kloc >> 3) * 16 + (kloc & 7) * 2) = pkv; \
      }                                                                     \
      { bf16x8 pa0 = *(const bf16x8*)(Ps + ql * 128 + swzc(ql, g) * 16);    \
        bf16x8 pa1 = *(const bf16x8*)(Ps + ql * 128 + swzc(ql, 4 + g) * 16);\
        _Pragma("unroll")                                                   \
        for (int df = 0; df < 4; ++df) {                                    \
            int d = df * 16 + c;                                            \
            bf16x8 vb0 = *(const bf16x8*)((VT) + d * 128 + swzc(d, g) * 16);     \
            bf16x8 vb1 = *(const bf16x8*)((VT) + d * 128 + swzc(d, 4 + g) * 16); \
            pacc[df] = __builtin_amdgcn_mfma_f32_16x16x32_bf16(pa0, vb0, pacc[df], 0, 0, 0); \
            pacc[df] = __builtin_amdgcn_mfma_f32_16x16x32_bf16(pa1, vb1, pacc[df], 0, 0, 0); \
        } } }

#define LOAD_K(KP, KTV)                                                     \
    { _Pragma("unroll")                                                     \
      for (int i = 0; i < 2; ++i) {                                         \
        int flat = i * NTHR + t, row = flat >> 3, ch = flat & 7;            \
        const float* src = Kg + (kbase + (KTV) * KT + row) * D_DIM + ch * 8;\
        float4 a = *(const float4*)src, b = *(const float4*)(src + 4);      \
        KP[i] = packbf(a, b);                                               \
      } }
#define STAGE_K(KS, KP)                                                     \
    { _Pragma("unroll")                                                     \
      for (int i = 0; i < 2; ++i) {                                         \
        int flat = i * NTHR + t, row = flat >> 3, ch = flat & 7;            \
        *(u32x4*)((KS) + row * 128 + swzc(row, ch) * 16) = KP[i];           \
      } }
#define LOAD_V(VP, KTV)                                                     \
    { const float* src = Vg + (kbase + (KTV) * KT + k0v) * D_DIM + dgv * 8; \
      float4 a = *(const float4*)src, b = *(const float4*)(src + 4);        \
      float4 e4 = *(const float4*)(src + D_DIM);                            \
      float4 f4 = *(const float4*)(src + D_DIM + 4);                        \
      VP[0] = (unsigned)f2bf(a.x) | ((unsigned)f2bf(e4.x) << 16);           \
      VP[1] = (unsigned)f2bf(a.y) | ((unsigned)f2bf(e4.y) << 16);           \
      VP[2] = (unsigned)f2bf(a.z) | ((unsigned)f2bf(e4.z) << 16);           \
      VP[3] = (unsigned)f2bf(a.w) | ((unsigned)f2bf(e4.w) << 16);           \
      VP[4] = (unsigned)f2bf(b.x) | ((unsigned)f2bf(f4.x) << 16);           \
      VP[5] = (unsigned)f2bf(b.y) | ((unsigned)f2bf(f4.y) << 16);           \
      VP[6] = (unsigned)f2bf(b.z) | ((unsigned)f2bf(f4.z) << 16);           \
      VP[7] = (unsigned)f2bf(b.w) | ((unsigned)f2bf(f4.w) << 16); }
#define STAGE_V(VT, VP)                                                     \
    { _Pragma("unroll")                                                     \
      for (int jj = 0; jj < 8; ++jj) {                                      \
        int d = dgv * 8 + jj;                                               \
        *(unsigned*)((VT) + d * 128 + swzc(d, k0v >> 3) * 16 + (k0v & 7) * 2) = VP[jj]; \
      } }

__global__ __launch_bounds__(NTHR, 4)
void attn_fused_reg(const float* __restrict__ Qg, const float* __restrict__ Kg,
                    const float* __restrict__ Vg,
                    const unsigned char* __restrict__ maskB,
                    const int* __restrict__ flagp,
                    unsigned short* __restrict__ bitsWS, int useWS,
                    float* __restrict__ attnOut, float* __restrict__ probOut) {
    __shared__ unsigned char sm[40960];
    unsigned char* Ks0 = sm;
    unsigned char* Ks1 = sm + 8192;
    unsigned char* Vt0 = sm + 16384;
    unsigned char* Vt1 = sm + 24576;
    unsigned char* Ps  = sm + 32768;

    const int t = threadIdx.x;
    const int lane = t & 63, w = t >> 6, c = lane & 15, g = lane >> 4;
    (void)lane;

    const int orig = blockIdx.x;
    const int virt = (orig & 7) * 128 + (orig >> 3);
    const int qt = virt & 31, bh = virt >> 5;
    const int mask32 = *flagp;
    const int* maskI = (const int*)maskB;
    (void)maskI;

    const int qrowbase = bh * S_LEN + qt * QT;
    const int kbase = bh * S_LEN;
    const int ql = w * 16 + c;
    const unsigned rowoff = (unsigned)(qrowbase + ql) * (unsigned)S_LEN;
    const unsigned bitbase = (unsigned)virt * NKT * NTHR + (unsigned)t;
    const int dgv = t & 7, k0v = (t >> 3) * 2;

    #pragma unroll
    for (int i = 0; i < 2; ++i) {
        int flat = i * NTHR + t, row = flat >> 3, ch = flat & 7;
        const float* src = Qg + (qrowbase + row) * D_DIM + ch * 8;
        float4 a = *(const float4*)src, b = *(const float4*)(src + 4);
        *(u32x4*)(Ps + row * 128 + swzc(row, ch) * 16) =
            packbf(scale4(a, 0.125f), scale4(b, 0.125f));
    }
    __syncthreads();
    bf16x8 qf0 = *(const bf16x8*)(Ps + ql * 128 + swzc(ql, g) * 16);
    bf16x8 qf1 = *(const bf16x8*)(Ps + ql * 128 + swzc(ql, 4 + g) * 16);
    __syncthreads();

    float psum = 0.f;
    u32x4 kpA[2], kpB[2];
    unsigned bA, bB;
    LOAD_K(kpA, 0)
    LOAD_MBITS(bA, 0)

    for (int j = 0; j < NKT / 2; ++j) {
        const int ktA = 2 * j, ktB = 2 * j + 1;
        STAGE_K(Ks0, kpA)
        LOAD_K(kpB, ktB)
        LOAD_MBITS(bB, ktB)
        __syncthreads();
        PH1_TILE(Ks0, bA)
        if (useWS) bitsWS[bitbase + (unsigned)ktA * NTHR] = (unsigned short)bA;
        STAGE_K(Ks1, kpB)
        if (j + 1 < NKT / 2) {
            LOAD_K(kpA, ktA + 2)
            LOAD_MBITS(bA, ktA + 2)
        }
        __syncthreads();
        PH1_TILE(Ks1, bB)
        if (useWS) bitsWS[bitbase + (unsigned)ktB * NTHR] = (unsigned short)bB;
    }

    float s = psum;
    s += __shfl_xor(s, 16, 64);
    s += __shfl_xor(s, 32, 64);
    const float rinv = 1.0f / s;

    f32x4 pacc[4];
    #pragma unroll
    for (int d = 0; d < 4; ++d) pacc[d] = (f32x4){0.f, 0.f, 0.f, 0.f};

    unsigned vpA[8], vpB[8];
    LOAD_K(kpA, 0)
    LOAD_V(vpA, 0)
    LOAD_BITS2(bA, 0)
    __syncthreads();

    for (int j = 0; j < NKT / 2; ++j) {
        const int ktA = 2 * j, ktB = 2 * j + 1;
        STAGE_K(Ks0, kpA)
        STAGE_V(Vt0, vpA)
        LOAD_K(kpB, ktB)
        LOAD_V(vpB, ktB)
        LOAD_BITS2(bB, ktB)
        __syncthreads();
        PH2_TILE(Ks0, Vt0, bA, ktA)
        STAGE_K(Ks1, kpB)
        STAGE_V(Vt1, vpB)
        if (j + 1 < NKT / 2) {
            LOAD_K(kpA, ktA + 2)
            LOAD_V(vpA, ktA + 2)
            LOAD_BITS2(bA, ktA + 2)
        }
        __syncthreads();
        PH2_TILE(Ks1, Vt1, bB, ktB)
    }

    #pragma unroll
    for (int df = 0; df < 4; ++df)
        #pragma unroll
        for (int r = 0; r < 4; ++r) {
            int qe = w * 16 + g * 4 + r;
            probOut[(long long)(qrowbase + qe) * D_DIM + df * 16 + c] = pacc[df][r];
        }
}

// -------------------------------------------------------------------------
extern "C" void kernel_launch(void* const* d_in, const int* in_sizes, int n_in,
                              void* d_out, int out_size, void* d_ws, size_t ws_size,
                              hipStream_t stream) {
    const float* Q = (const float*)d_in[0];
    const float* K = (const float*)d_in[1];
    const float* V = (const float*)d_in[2];
    const unsigned char* mask = (const unsigned char*)d_in[3];

    float* prob = (float*)d_out;
    float* attn = (float*)d_out + PROB_ELEMS;

    const size_t bits_bytes = (size_t)NBLK * NKT * NTHR * 2ull;   // 16.78 MB
    const size_t kbf_bytes  = 8388608ull;                          // per tensor
    int* flag = (int*)d_ws;
    unsigned short* bitsWS = (unsigned short*)((char*)d_ws + 256);
    unsigned* Kf = (unsigned*)((char*)d_ws + 256 + bits_bytes);
    unsigned* Vf = (unsigned*)((char*)d_ws + 256 + bits_bytes + kbf_bytes);

    const int useWS   = (ws_size >= 256 + bits_bytes) ? 1 : 0;
    const int usePrep = (ws_size >= 256 + bits_bytes + 2 * kbf_bytes) ? 1 : 0;

    mask_probe_kernel<<<1, 64, 0, stream>>>((const unsigned int*)mask, flag);
    if (usePrep) {
        kv_prep_frag<<<(KFRAG_T + VFRAG_T) / 256, 256, 0, stream>>>(K, V, Kf, Vf);
        attn_fused_frag<<<NBLK, NTHR, 0, stream>>>(Q, Kf, Vf, mask, flag,
                                                   bitsWS, useWS, attn, prob);
    } else {
        attn_fused_reg<<<NBLK, NTHR, 0, stream>>>(Q, K, V, mask, flag,
                                                  bitsWS, useWS, attn, prob);
    }
}